// Round 6
// baseline (196.862 us; speedup 1.0000x reference)
//
#include <hip/hip_runtime.h>
#include <stdint.h>

// Problem: x[B=32][N=8192][D=64] fp32 -> out[B][D][D][D] fp32 (centered 3rd moment)
#define B_SZ 32
#define N_SZ 8192
#define D_SZ 64

typedef _Float16 half8 __attribute__((ext_vector_type(8)));
typedef float f32x4 __attribute__((ext_vector_type(4)));

#define AS1 __attribute__((address_space(1)))
#define AS3 __attribute__((address_space(3)))

#define MFMA16(Aop, Bop, Cop) __builtin_amdgcn_mfma_f32_16x16x32_f16(Aop, Bop, Cop, 0, 0, 0)

// Granule layout v1 (proven 0-conflict): per 64-n granule, chunk (d, cc)
// [8 halves, n = cc*8..+8] stored at d*64 + (cc ^ (d&7))*8 halves.
//
// v3.1 (R5): ej=2 acc->AGPR main loop verified clean (WRITE 33MB, VGPR 88),
//   but wall 86us vs 41us matrix floor: the per-iter asm fences
//   (lgkmcnt(0)/stage/vmcnt(8)) forced strict LDS-phase / MFMA-phase
//   alternation per wave -> CU pipes alternate too (44us LDS + 41us matrix
//   ~= 86us measured). R0's barriered mega-T body overlapped BETTER because
//   the compiler could slide granule-2 ds_reads under granule-1 MFMAs.
// v4 (this round): register prefetch decouples the phases (T14):
//   tail of iter T: vmcnt(0) (stage from iter-top has landed ~1500cyc later,
//   no stall) then ds_read all 12 fragments of granule T+1 into VGPRs
//   FA[2][4]/FS[2][2]. Compute phase runs register-only; next-granule
//   ds_reads overlap other waves' MFMAs. Buffer WAR safety is by program
//   order (frags consumed by MFMAs a full iteration before re-stage) ->
//   zero lgkmcnt fences. ~150 VGPR + 80 AGPR fits 2 blocks/CU.

// ---------------------------------------------------------------------------
// Kernel 1: per-batch column sums. grid = 32 b * 32 slabs (256 n-rows each).
// ---------------------------------------------------------------------------
__global__ __launch_bounds__(256) void tp_mean_kernel(const float* __restrict__ x,
                                                      float* __restrict__ sums) {
    const int b    = blockIdx.x >> 5;
    const int slab = blockIdx.x & 31;
    const int d4   = threadIdx.x & 15;
    const int nr   = threadIdx.x >> 4;
    const float* base = x + (size_t)b * (N_SZ * D_SZ) + (size_t)(slab * 256 + nr) * D_SZ + d4 * 4;
    f32x4 s = {0.f, 0.f, 0.f, 0.f};
#pragma unroll
    for (int i = 0; i < 16; i++)
        s += *(const f32x4*)(base + i * 16 * D_SZ);
    __shared__ f32x4 red[16][16];
    red[nr][d4] = s;
    __syncthreads();
    if (threadIdx.x < 16) {
        f32x4 tot = red[0][threadIdx.x];
#pragma unroll
        for (int j = 1; j < 16; j++) tot += red[j][threadIdx.x];
        atomicAdd(&sums[b * 64 + threadIdx.x * 4 + 0], tot[0]);
        atomicAdd(&sums[b * 64 + threadIdx.x * 4 + 1], tot[1]);
        atomicAdd(&sums[b * 64 + threadIdx.x * 4 + 2], tot[2]);
        atomicAdd(&sums[b * 64 + threadIdx.x * 4 + 3], tot[3]);
    }
}

// ---------------------------------------------------------------------------
// Kernel 2: center, cast fp16, register transpose into layout v1 (verbatim).
// ---------------------------------------------------------------------------
__global__ __launch_bounds__(256) void tp_transpose_kernel(const float* __restrict__ x,
                                                           const float* __restrict__ sums,
                                                           _Float16* __restrict__ xcS) {
    const int b    = blockIdx.x >> 6;
    const int tp   = blockIdx.x & 63;
    const int t    = threadIdx.x;
    const int tile = tp * 2 + (t >> 7);
    const int r8   = (t >> 4) & 7;
    const int dq   = t & 15;

    f32x4 mean4 = *(const f32x4*)(sums + b * 64 + dq * 4) * (1.0f / (float)N_SZ);
    const float* src = x + (size_t)b * (N_SZ * D_SZ) + (size_t)(tile * 64 + r8 * 8) * D_SZ + dq * 4;
    f32x4 v[8];
#pragma unroll
    for (int i = 0; i < 8; i++)
        v[i] = *(const f32x4*)(src + i * D_SZ);

    _Float16* dstb = xcS + (size_t)b * (N_SZ * D_SZ) + (size_t)tile * 4096;
#pragma unroll
    for (int c = 0; c < 4; c++) {
        const int d   = dq * 4 + c;
        const int ccp = r8 ^ (d & 7);
        half8 o;
#pragma unroll
        for (int i = 0; i < 8; i++)
            o[i] = (_Float16)(v[i][c] - mean4[c]);
        *(half8*)(dstb + d * 64 + ccp * 8) = o;
    }
}

// ---------------------------------------------------------------------------
// Kernel 3 v4: grid (32 b, 32 eg), block 256 = 4 waves = 4 N-quarters,
// each wave computes ej=2 e-values (e0 = eg*2). LDS = 2 bufs x 4 h x 8KB.
// Per wave per T: compute 40 MFMA from prefetched regs FA/FS; tail:
// vmcnt(0) + ds_read next granule's 12 b128 into FA/FS. Barrier-free.
// acc[2][10] = 80 regs in AGPRs. 4-way cross-h reduction epilogue;
// wave h=0 stores e0, h=1 stores e0+1 via statically-bound storeE.
// ---------------------------------------------------------------------------
__global__ __launch_bounds__(256, 2) void tp_gemm_kernel(const _Float16* __restrict__ xcS,
                                                         float* __restrict__ out) {
    const int b    = blockIdx.x;          // 0..31
    const int eg   = blockIdx.y;          // 0..31
    const int tid  = threadIdx.x;
    const int lane = tid & 63;
    const int h    = tid >> 6;            // 0..3 N-quarter
    const int q    = lane >> 4;           // 0..3
    const int m    = lane & 15;
    const int e0   = eg * 2;

    __shared__ __align__(16) char ldsraw[65536];   // 2 bufs x 4 h x 8KB
    float* redL = (float*)ldsraw;                  // aliased for reduction (30KB)

    // staging source: wave h owns quarter h, one full 8KB granule per T
    const _Float16* gbase = xcS + (size_t)b * (N_SZ * D_SZ)
                          + (size_t)h * (N_SZ / 4) * D_SZ
                          + (size_t)(lane * 8);

    // fragment byte offsets (layout v1) for ks=0; ks=1 is offset ^ 64
    // (c = ks*4+q = q^4 for ks=1, and (x^4)*16 = x*16 ^ 64).
    int aOff[4], sOff[2];
#pragma unroll
    for (int i = 0; i < 4; i++) {
        const int r = i * 16 + m;
        aOff[i] = r * 128 + ((q ^ (r & 7)) * 16);
    }
#pragma unroll
    for (int j = 0; j < 2; j++) {
        const int e = e0 + j;
        sOff[j] = e * 128 + ((q ^ (e & 7)) * 16);
    }

    f32x4 acc[2][10];
#pragma unroll
    for (int ej = 0; ej < 2; ej++)
#pragma unroll
        for (int k = 0; k < 10; k++)
            acc[ej][k] = (f32x4){0.f, 0.f, 0.f, 0.f};

    // stage granule T of my quarter into buffer bi (wave-private 8KB region)
    auto stage = [&](int T, int bi) {
        _Float16* lb = (_Float16*)(ldsraw + bi * 32768 + h * 8192);
        const _Float16* gb = gbase + (size_t)T * 4096;
#pragma unroll
        for (int k = 0; k < 8; k++)
            __builtin_amdgcn_global_load_lds(
                (const AS1 void*)(gb + k * 512),
                (AS3 void*)(lb + k * 512), 16, 0, 0);
    };

    // register fragments for the granule being computed (prefetched)
    half8 FA[2][4], FS[2][2];
    auto prefetch = [&](int bi) {
        const char* tb = ldsraw + bi * 32768 + h * 8192;
#pragma unroll
        for (int ks = 0; ks < 2; ks++) {
            const int kx = ks << 6;
#pragma unroll
            for (int i = 0; i < 4; i++)
                FA[ks][i] = *(const half8*)(tb + (aOff[i] ^ kx));
#pragma unroll
            for (int j = 0; j < 2; j++)
                FS[ks][j] = *(const half8*)(tb + (sOff[j] ^ kx));
        }
    };

    stage(0, 0);
    asm volatile("s_waitcnt vmcnt(0)" ::: "memory");
    prefetch(0);

    for (int T = 0; T < 32; T++) {
        if (T < 31) stage(T + 1, (T + 1) & 1);   // lands during compute below
#pragma unroll
        for (int ks = 0; ks < 2; ks++) {
#pragma unroll
            for (int ej = 0; ej < 2; ej++) {
                half8 S  = FS[ks][ej];
                half8 P0 = FA[ks][0] * S;   // fold xc[n,e] into A (v_pk_mul_f16)
                half8 P1 = FA[ks][1] * S;
                half8 P2 = FA[ks][2] * S;
                half8 P3 = FA[ks][3] * S;
                acc[ej][0] = MFMA16(P0, FA[ks][0], acc[ej][0]);
                acc[ej][1] = MFMA16(P0, FA[ks][1], acc[ej][1]);
                acc[ej][2] = MFMA16(P0, FA[ks][2], acc[ej][2]);
                acc[ej][3] = MFMA16(P0, FA[ks][3], acc[ej][3]);
                acc[ej][4] = MFMA16(P1, FA[ks][1], acc[ej][4]);
                acc[ej][5] = MFMA16(P1, FA[ks][2], acc[ej][5]);
                acc[ej][6] = MFMA16(P1, FA[ks][3], acc[ej][6]);
                acc[ej][7] = MFMA16(P2, FA[ks][2], acc[ej][7]);
                acc[ej][8] = MFMA16(P2, FA[ks][3], acc[ej][8]);
                acc[ej][9] = MFMA16(P3, FA[ks][3], acc[ej][9]);
            }
        }
        if (T < 31) {
            // stage(T+1) was issued one full compute phase ago -> no stall;
            // after this, buf[(T+1)&1] is readable. Prefetch its fragments;
            // these ds_reads overlap other waves' MFMA phases.
            asm volatile("s_waitcnt vmcnt(0)" ::: "memory");
            prefetch((T + 1) & 1);
        }
    }

    // ---- 4-way cross-h reduction, two rounds (30KB dumps each) ----
    __syncthreads();                      // end of main loop, LDS alias reuse
    const int rb = lane * 4;
    // round 0: h=1,2,3 dump acc[0]; h=0 gathers (owns e0)
    if (h != 0) {
        float* dst = redL + (h - 1) * 2560 + rb;
#pragma unroll
        for (int k = 0; k < 10; k++)
            *(f32x4*)(dst + k * 256) = acc[0][k];
    }
    __syncthreads();
    if (h == 0) {
#pragma unroll
        for (int k = 0; k < 10; k++) {
            const float* s0 = redL + k * 256 + rb;
            acc[0][k] += *(const f32x4*)(s0);
            acc[0][k] += *(const f32x4*)(s0 + 2560);
            acc[0][k] += *(const f32x4*)(s0 + 5120);
        }
    }
    __syncthreads();
    // round 1: h=0,2,3 dump acc[1]; h=1 gathers (owns e0+1)
    if (h != 1) {
        const int region = (h == 0) ? 0 : (h - 1);
        float* dst = redL + region * 2560 + rb;
#pragma unroll
        for (int k = 0; k < 10; k++)
            *(f32x4*)(dst + k * 256) = acc[1][k];
    }
    __syncthreads();
    if (h == 1) {
#pragma unroll
        for (int k = 0; k < 10; k++) {
            const float* s0 = redL + k * 256 + rb;
            acc[1][k] += *(const f32x4*)(s0);
            acc[1][k] += *(const f32x4*)(s0 + 2560);
            acc[1][k] += *(const f32x4*)(s0 + 5120);
        }
    }

    // ---- stores: statically-bound accumulator (rule #20: no runtime h
    // index into acc). Wave h=0 stores e0 from acc[0]; h=1 stores e0+1
    // from acc[1].
    const float invn = 1.0f / (float)N_SZ;
    float* outb = out + (size_t)b * (D_SZ * D_SZ * D_SZ);
    auto storeE = [&](const f32x4 (&accr)[10], int e) {
        int idx = 0;
        // C/D layout (verified): col = lane&15 = f-within-block, row = q*4+reg
#pragma unroll
        for (int i = 0; i < 4; i++) {
#pragma unroll
            for (int j = i; j < 4; j++, idx++) {
                f32x4 vsc = accr[idx] * invn;
#pragma unroll
                for (int r = 0; r < 4; r++)
                    outb[(size_t)(16 * i + q * 4 + r) * 4096 + e * 64 + 16 * j + m] = vsc[r];
                if (i != j) {
                    *(f32x4*)&outb[(size_t)(16 * j + m) * 4096 + e * 64 + 16 * i + q * 4] = vsc;
                }
            }
        }
    };
    if (h == 0) {
        storeE(acc[0], e0);
    } else if (h == 1) {
        storeE(acc[1], e0 + 1);
    }
}

// ---------------------------------------------------------------------------
extern "C" void kernel_launch(void* const* d_in, const int* in_sizes, int n_in,
                              void* d_out, int out_size, void* d_ws, size_t ws_size,
                              hipStream_t stream) {
    const float* x = (const float*)d_in[0];
    float* out = (float*)d_out;

    float* sums = (float*)d_ws;                           // 8 KB
    _Float16* xcS = (_Float16*)((char*)d_ws + 8192);      // 33.5 MB fp16

    hipMemsetAsync(sums, 0, B_SZ * D_SZ * sizeof(float), stream);
    tp_mean_kernel<<<dim3(B_SZ * 32), 256, 0, stream>>>(x, sums);
    tp_transpose_kernel<<<dim3(B_SZ * 64), 256, 0, stream>>>(x, sums, xcS);
    tp_gemm_kernel<<<dim3(32, 32), 256, 0, stream>>>(xcS, out);
}